// Round 3
// baseline (378.195 us; speedup 1.0000x reference)
//
#include <hip/hip_runtime.h>

#define BATCH 128
#define NCELL 2048
#define OWN 512             // cells owned per block
#define HALO 256            // >= stepnum-2 = 254
#define WIDTH 1024          // OWN + 2*HALO
#define NTHREADS 256        // WIDTH / 4 cells per thread
#define GUARD 4             // LDS guard cells each side (edge replication)

typedef float f32x4 __attribute__((ext_vector_type(4)));

// flux(u) expanded to a polynomial (beta = 0.1):
// f(u)  = 1.5u + 0.00625u^2 - 0.5166666...u^3 + 0.0125u^4 - 0.00208333...u^6
// f'(u) = 1.5 + 0.0125u - 1.55u^2 + 0.05u^3 - 0.0125u^5
__device__ __forceinline__ float flux_h(float u, float u2) {
    float h = fmaf(u2, -0.0020833333333333333f, 0.0125f);
    h = fmaf(u, h, -0.5166666666666667f);
    h = fmaf(u, h, 0.00625f);
    h = fmaf(u, h, 1.5f);
    return u * h;
}
__device__ __forceinline__ float aprime_h(float u, float u2) {
    float h = fmaf(u2, -0.0125f, 0.05f);
    h = fmaf(u, h, -1.55f);
    h = fmaf(u, h, 0.0125f);
    h = fmaf(u, h, 1.5f);
    return fabsf(h);
}

// One local time step on the 12-cell register window.
// Window index i <-> global cell g0m4 + i. At entry, indices [J, 11-J] are
// valid; updates produce valid [J+1, 10-J]. Arithmetic is bitwise-identical
// (same op order) to the per-step kernel, so results match exactly.
template <int J>
__device__ __forceinline__ void substep(float (&w)[12], int g0m4, int lo,
                                        int hi, float c) {
    float f[12], a[12];
#pragma unroll
    for (int i = J; i <= 11 - J; ++i) {
        const float uu = w[i], uu2 = uu * uu;
        f[i] = flux_h(uu, uu2);
        a[i] = aprime_h(uu, uu2);
    }
    float fh[11];
#pragma unroll
    for (int i = J; i <= 10 - J; ++i) {
        fh[i] = 0.5f * (f[i] + f[i + 1])
              - 0.5f * fmaxf(a[i], a[i + 1]) * (w[i + 1] - w[i]);
    }
    float un[12];
#pragma unroll
    for (int i = J + 1; i <= 10 - J; ++i) {
        const int g = g0m4 + i;
        const float v = w[i] - c * (fh[i] - fh[i - 1]);
        un[i] = (g >= lo && g <= hi) ? v : w[i];
    }
    // Outflow BC: cell 0 copies cell 1's interior update; cell N-1 copies
    // N-2's. When the needed neighbor is outside the valid window range the
    // copy is skipped — provably only happens in threads whose owned cells
    // lie outside the row (never stored, never consumed as real input).
#pragma unroll
    for (int i = J + 1; i <= 10 - J; ++i) {
        const int g = g0m4 + i;
        float v = un[i];
        if (i <= 9 - J)  v = (g == 0) ? un[i + 1] : v;
        if (i >= J + 2)  v = (g == NCELL - 1) ? un[i - 1] : v;
        w[i] = v;
    }
}

// Trapezoid time-tiling, k=4 steps per barrier round.
// 4 blocks per batch row (grid=512 -> 2 blocks/CU). Each block owns 512
// cells + 254-cell shrinking halo. Per ROUND (4 time steps): 1 ds_write_b128
// of own cells, 1 lgkm-only barrier, 2 ds_read_b128 (4-cell halo each side
// from a guard-padded LDS row), then 4 fully-register substeps with 4
// nontemporal float4 trajectory stores. Barriers: 255 -> 64.
__global__ __launch_bounds__(NTHREADS)
void VariantCoeLinear1d_kernel(const float* __restrict__ init,
                               const int* __restrict__ stepnum_p,
                               float* __restrict__ out) {
    __shared__ float ubuf[2][WIDTH + 2 * GUARD];

    const int b = blockIdx.x;
    const int row = b >> 2;
    const int q = b & 3;
    const int t = threadIdx.x;
    const int S = *stepnum_p;
    const float c = 0.4096f;             // float(DT/DX)

    const int ownedLo = q * OWN;
    const int ownedHi = ownedLo + OWN - 1;
    const int base = ownedLo - HALO;     // global index of LDS payload cell 0
    const int li = t << 2;               // my first LDS payload cell
    const int g0 = base + li;            // my first global cell
    const int g0m4 = g0 - 4;             // global index of window cell 0

    // ---- load init (clamped at row edges) ----
    const float* rin = init + (size_t)row * NCELL;
    float w[12];
    if (g0 >= 0 && g0 + 3 < NCELL) {
        float4 v = *(const float4*)(rin + g0);
        w[4] = v.x; w[5] = v.y; w[6] = v.z; w[7] = v.w;
    } else {
        w[4] = rin[min(max(g0 + 0, 0), NCELL - 1)];
        w[5] = rin[min(max(g0 + 1, 0), NCELL - 1)];
        w[6] = rin[min(max(g0 + 2, 0), NCELL - 1)];
        w[7] = rin[min(max(g0 + 3, 0), NCELL - 1)];
    }

    const bool owned = (t >= HALO / 4) && (t < (HALO + OWN) / 4); // 64..191
    const size_t stride = (size_t)BATCH * NCELL;
    float* op = out + (size_t)row * NCELL + g0;   // step-0 output address
    if (owned) {
        __builtin_nontemporal_store((f32x4){w[4], w[5], w[6], w[7]},
                                    (f32x4*)op);
    }

    int cur = 0;
    for (int s = 1; s < S; s += 4) {
        float* ub = ubuf[cur];
        *(float4*)&ub[li + GUARD] = make_float4(w[4], w[5], w[6], w[7]);
        // Guard cells replicate the row's outermost LDS value (same clamp
        // semantics as the per-step kernel's index clamping).
        if (t == 0)
            *(float4*)&ub[0] = make_float4(w[4], w[4], w[4], w[4]);
        if (t == NTHREADS - 1)
            *(float4*)&ub[WIDTH + GUARD] = make_float4(w[7], w[7], w[7], w[7]);
        // LDS-only fence + barrier (trajectory stores stay in flight).
        asm volatile("s_waitcnt lgkmcnt(0)\n\ts_barrier" ::: "memory");

        const int rem0 = (S - 1) - s;                // widest region this round
        const int lo0 = max(ownedLo - rem0, 0);
        const int hi0 = min(ownedHi + rem0, NCELL - 1);

        // Skip threads whose whole window is outside the active region
        // (region only shrinks, so skipped threads stay skipped; owned
        // threads are always active).
        if (g0 + 7 >= lo0 && g0m4 <= hi0) {
            const float4 hl = *(const float4*)&ub[li];             // g0-4..g0-1
            const float4 hr = *(const float4*)&ub[li + GUARD + 4]; // g0+4..g0+7
            w[0] = hl.x; w[1] = hl.y; w[2]  = hl.z; w[3]  = hl.w;
            w[8] = hr.x; w[9] = hr.y; w[10] = hr.z; w[11] = hr.w;

            // ---- substep s ----
            substep<0>(w, g0m4, lo0, hi0, c);
            op += stride;
            if (owned)
                __builtin_nontemporal_store((f32x4){w[4], w[5], w[6], w[7]},
                                            (f32x4*)op);
            // ---- substep s+1 ----
            if (s + 1 < S) {
                const int rem = rem0 - 1;
                substep<1>(w, g0m4, max(ownedLo - rem, 0),
                           min(ownedHi + rem, NCELL - 1), c);
                op += stride;
                if (owned)
                    __builtin_nontemporal_store(
                        (f32x4){w[4], w[5], w[6], w[7]}, (f32x4*)op);
                // ---- substep s+2 ----
                if (s + 2 < S) {
                    const int rem2 = rem0 - 2;
                    substep<2>(w, g0m4, max(ownedLo - rem2, 0),
                               min(ownedHi + rem2, NCELL - 1), c);
                    op += stride;
                    if (owned)
                        __builtin_nontemporal_store(
                            (f32x4){w[4], w[5], w[6], w[7]}, (f32x4*)op);
                    // ---- substep s+3 ----
                    if (s + 3 < S) {
                        const int rem3 = rem0 - 3;
                        substep<3>(w, g0m4, max(ownedLo - rem3, 0),
                                   min(ownedHi + rem3, NCELL - 1), c);
                        op += stride;
                        if (owned)
                            __builtin_nontemporal_store(
                                (f32x4){w[4], w[5], w[6], w[7]}, (f32x4*)op);
                    }
                }
            }
        }
        cur ^= 1;
    }
}

extern "C" void kernel_launch(void* const* d_in, const int* in_sizes, int n_in,
                              void* d_out, int out_size, void* d_ws, size_t ws_size,
                              hipStream_t stream) {
    const float* init = (const float*)d_in[0];
    const int* stepnum = (const int*)d_in[1];
    float* out = (float*)d_out;

    dim3 grid(BATCH * 4);   // 4 trapezoid blocks per row -> 2 blocks/CU
    dim3 block(NTHREADS);
    VariantCoeLinear1d_kernel<<<grid, block, 0, stream>>>(init, stepnum, out);
}

// Round 5
// 377.182 us; speedup vs baseline: 1.0027x; 1.0027x over previous
//
#include <hip/hip_runtime.h>

#define BATCH 128
#define NCELL 2048
#define OWN 512             // cells owned per block
#define HALO 128            // >= max per-dispatch remaining steps (127)
#define WIDTH 768           // OWN + 2*HALO
#define NTHREADS 192        // WIDTH / 4 cells per thread
#define CHUNK 128           // max time advances per dispatch

typedef float f32x4 __attribute__((ext_vector_type(4)));

// flux(u) expanded to a polynomial (beta = 0.1):
// f(u)  = 1.5u + 0.00625u^2 - 0.5166666...u^3 + 0.0125u^4 - 0.00208333...u^6
// f'(u) = 1.5 + 0.0125u - 1.55u^2 + 0.05u^3 - 0.0125u^5
__device__ __forceinline__ float flux_h(float u, float u2) {
    float h = fmaf(u2, -0.0020833333333333333f, 0.0125f);
    h = fmaf(u, h, -0.5166666666666667f);
    h = fmaf(u, h, 0.00625f);
    h = fmaf(u, h, 1.5f);
    return u * h;
}
__device__ __forceinline__ float fp_h(float u, float u2) {   // signed f'(u)
    float h = fmaf(u2, -0.0125f, 0.05f);
    h = fmaf(u, h, -1.55f);
    h = fmaf(u, h, 0.0125f);
    h = fmaf(u, h, 1.5f);
    return h;   // |.| applied as free VOP3 abs modifier at the fmaxf consumer
}

// Trapezoid time-tiling, chunked over 2 dispatches (VALU-bound per rocprof:
// VALUBusy 79%). Chunking halves the halo: HALO=128 -> avg active width
// 1.25x owned (was 1.50x at HALO=256). Dispatch 1 reloads the complete
// state from out[CHUNK] (every cell is owned by exactly one block, so the
// stored slice is globally exact; same-stream ordering + kernel-boundary
// coherence make it visible). Inner loop is the proven k=1 per-step
// structure with bitwise-identical arithmetic; interior threads take a
// cndmask-free fast path.
__global__ __launch_bounds__(NTHREADS)
void VariantCoeLinear1d_kernel(const float* __restrict__ src,
                               const int* __restrict__ stepnum_p,
                               float* __restrict__ out,
                               int s_begin, int store_init) {
    __shared__ float ubuf[2][WIDTH];

    const int b = blockIdx.x;
    const int row = b >> 2;
    const int q = b & 3;
    const int t = threadIdx.x;
    const int S = *stepnum_p;
    const int s_last = min(s_begin + (CHUNK - 1), S - 1); // last step this dispatch
    const float c = 0.4096f;             // float(DT/DX)

    const int ownedLo = q * OWN;
    const int ownedHi = ownedLo + OWN - 1;
    const int base = ownedLo - HALO;     // global index of LDS cell 0
    const int li = t << 2;               // my first LDS cell
    const int g0 = base + li;            // my first global cell

    // ---- load state at step s_begin-1 (clamped at row edges; clamped halo
    //      lanes are provably never consumed by active-region updates) ----
    const float* rin = src + (size_t)row * NCELL;
    float u0, u1, u2, u3;
    if (g0 >= 0 && g0 + 3 < NCELL) {
        float4 v = *(const float4*)(rin + g0);
        u0 = v.x; u1 = v.y; u2 = v.z; u3 = v.w;
    } else {
        u0 = rin[min(max(g0 + 0, 0), NCELL - 1)];
        u1 = rin[min(max(g0 + 1, 0), NCELL - 1)];
        u2 = rin[min(max(g0 + 2, 0), NCELL - 1)];
        u3 = rin[min(max(g0 + 3, 0), NCELL - 1)];
    }

    const bool owned = (t >= HALO / 4) && (t < (HALO + OWN) / 4); // 32..159
    const bool isL = (g0 == 0);
    const bool isR = (g0 + 3 == NCELL - 1);
    const size_t stride = (size_t)BATCH * NCELL;
    float* op = out + ((size_t)(s_begin - 1) * BATCH + row) * NCELL + g0;
    if (store_init && owned) {
        __builtin_nontemporal_store((f32x4){u0, u1, u2, u3}, (f32x4*)op);
    }

    int cur = 0;
    for (int s = s_begin; s <= s_last; ++s) {
        float* ub = ubuf[cur];
        *(float4*)&ub[li] = make_float4(u0, u1, u2, u3);
        // LDS-only fence + barrier (trajectory stores stay in flight).
        asm volatile("s_waitcnt lgkmcnt(0)\n\ts_barrier" ::: "memory");

        const int rem = s_last - s;                // dispatch-local remaining
        const int lo = max(ownedLo - rem, 0);      // active region this step
        const int hi = min(ownedHi + rem, NCELL - 1);
        op += stride;

        if (g0 + 3 >= lo && g0 <= hi) {
            const float ulm = ub[max(li - 1, 0)];
            const float ulp = ub[min(li + 4, WIDTH - 1)];
            float ul[6] = {ulm, u0, u1, u2, u3, ulp};
            float f[6], a[6];
#pragma unroll
            for (int j = 0; j < 6; ++j) {
                const float uu = ul[j], uu2 = uu * uu;
                f[j] = flux_h(uu, uu2);
                a[j] = fp_h(uu, uu2);
            }
            float fh[5];
#pragma unroll
            for (int j = 0; j < 5; ++j) {
                fh[j] = 0.5f * (f[j] + f[j + 1])
                      - 0.5f * fmaxf(fabsf(a[j]), fabsf(a[j + 1]))
                             * (ul[j + 1] - ul[j]);
            }
            if (g0 >= lo && g0 + 3 <= hi && !isL && !isR) {
                // Fully-interior fast path: no per-cell range cndmask, no BC.
                u0 = ul[1] - c * (fh[1] - fh[0]);
                u1 = ul[2] - c * (fh[2] - fh[1]);
                u2 = ul[3] - c * (fh[3] - fh[2]);
                u3 = ul[4] - c * (fh[4] - fh[3]);
            } else {
                float un[4];
#pragma unroll
                for (int i = 0; i < 4; ++i) {
                    un[i] = ul[i + 1] - c * (fh[i + 1] - fh[i]);
                    const int g = g0 + i;
                    un[i] = (g >= lo && g <= hi) ? un[i] : ul[i + 1];
                }
                // Outflow BC (only row-edge cells):
                if (isL) un[0] = un[1];
                if (isR) un[3] = un[2];
                u0 = un[0]; u1 = un[1]; u2 = un[2]; u3 = un[3];
            }
            if (owned) {
                __builtin_nontemporal_store((f32x4){u0, u1, u2, u3},
                                            (f32x4*)op);
            }
        }
        cur ^= 1;
    }
}

extern "C" void kernel_launch(void* const* d_in, const int* in_sizes, int n_in,
                              void* d_out, int out_size, void* d_ws, size_t ws_size,
                              hipStream_t stream) {
    const float* init = (const float*)d_in[0];
    const int* stepnum = (const int*)d_in[1];
    float* out = (float*)d_out;
    const size_t stride = (size_t)BATCH * NCELL;

    dim3 grid(BATCH * 4);   // 4 trapezoid blocks per row -> 2 blocks/CU
    dim3 block(NTHREADS);
    // Dispatch 0: stores slice 0 + steps 1..128 (rem max 127 <= HALO).
    VariantCoeLinear1d_kernel<<<grid, block, 0, stream>>>(
        init, stepnum, out, 1, 1);
    // Dispatch 1: reloads complete state from slice 128, steps 129..S-1
    // (no-op if S <= 129; rem max 126 <= HALO).
    VariantCoeLinear1d_kernel<<<grid, block, 0, stream>>>(
        out + (size_t)CHUNK * stride, stepnum, out, CHUNK + 1, 0);
}